// Round 9
// baseline (917.339 us; speedup 1.0000x reference)
//
#include <hip/hip_runtime.h>
#include <math.h>

#define B 512
#define D 1024
#define H 512
#define C 48
#define K 3
#define T 25
#define DP1 1025
#define G4H 2048
#define NC 2112         // step GEMM N (padded): 2048 gates | 48 logits | 16 pad
#define NCV 2096        // valid cols
#define KP 1056         // padded K for x0/embed rows (multiple of 32)
#define FK 6304         // padded feat-K (6288 -> 6304)

typedef _Float16 f16;
typedef _Float16 half8 __attribute__((ext_vector_type(8)));
typedef float floatx4 __attribute__((ext_vector_type(4)));

__device__ __forceinline__ float sigf(float x){ return 1.0f/(1.0f+__expf(-x)); }
// NaN-safe fast tanh: tanh(x) = sign(x)*(1-t)/(1+t), t=exp(-2|x|) in (0,1]
__device__ __forceinline__ float tanhf_fast(float x){
    float t = __expf(-2.0f*fabsf(x));
    float r = (1.0f-t)/(1.0f+t);
    return x<0.f ? -r : r;
}

// ================= unified split-f16 MFMA GEMM =================
// template<NT, MODE>: NT = B n-tile (32/64); MODE 0 = plain A, MODE 1 = x0 feat gather.
// Counted-vmcnt pipeline: raw s_barrier + lgkmcnt-only wait -> next-tile global prefetch
// stays in flight across the barrier (T3/T4). MODE 1 defers float->f16 conversion to
// AFTER the MFMA block so A-load latency hides under MFMA.
template<int NT, int MODE>
__global__ __launch_bounds__(256)
void k_gemm(const f16* __restrict__ Ahi, const f16* __restrict__ Alo,
            const f16* __restrict__ Bhi, const f16* __restrict__ Blo,
            float* __restrict__ Cc, const float* __restrict__ bias,
            int M, int Nvalid, int Ktot, int lda, int ldb, int ldc,
            int ksl, size_t cstride, int MB, int Z, int zmaj,
            const f16* __restrict__ Yh, const f16* __restrict__ Yl,
            const float* __restrict__ Sf, const float* __restrict__ Rf)
{
    __shared__ __align__(16) f16 Ash[2][64][40];
    __shared__ __align__(16) f16 Asl[2][64][40];
    __shared__ __align__(16) f16 Bsh[2][NT][40];
    __shared__ __align__(16) f16 Bsl[2][NT][40];
    int t = threadIdx.x;
    int mblk, nblk, z;
    if (zmaj){
        // z-major: each XCD owns a K-slice -> its B-slice stays in per-XCD L2
        z = blockIdx.x % Z;
        int rest = blockIdx.x / Z;
        mblk = rest % MB; nblk = rest / MB;
    } else {
        // n-chunked: same-XCD blocks share an n-range (requires gridDim %8==0)
        int chunk = gridDim.x >> 3;
        int g = (blockIdx.x & 7)*chunk + (blockIdx.x >> 3);
        int mz = g % (MB*Z);
        nblk = g / (MB*Z);
        mblk = mz / Z;
        z    = mz % Z;
    }
    int m0 = mblk*64, n0 = nblk*NT;
    int kbase = z*ksl;
    int kcnt = (z==Z-1)? (Ktot-kbase) : ksl;
    int nIter = kcnt >> 5;
    int r = t>>2, seg = t&3;
    const bool ldB = (r < NT);
    half8 rah, ral, rbh, rbl;
    float4 fA0, fA1;

    auto LOAD = [&](int k0){
        int kk = k0 + seg*8;
        if (ldB){
            size_t off = (size_t)(n0+r)*ldb + kbase + kk;
            rbh = *(const half8*)(Bhi + off);
            rbl = *(const half8*)(Blo + off);
        }
        int m = m0 + r;
        if (MODE==0){
            if (m < M){
                size_t off = (size_t)m*lda + kbase + kk;
                rah = *(const half8*)(Ahi + off);
                ral = *(const half8*)(Alo + off);
            } else {
                #pragma unroll
                for (int i=0;i<8;i++){ rah[i]=(f16)0; ral[i]=(f16)0; }
            }
        } else {
            int kabs = kbase + kk;   // 8-aligned; source runs never straddle boundaries
            if (kabs < 144){
                rah = *(const half8*)(Yh + (size_t)m*144 + kabs);
                ral = *(const half8*)(Yl + (size_t)m*144 + kabs);
            } else if (kabs < 6288){
                int kp = kabs - 144;
                const float* src = (kp < 3*D)
                    ? (Sf + (size_t)(kp>>10)*(B*D) + (size_t)m*D + (kp&(D-1)))
                    : (Rf + (size_t)((kp-3*D)>>10)*(B*D) + (size_t)m*D + ((kp-3*D)&(D-1)));
                fA0 = *(const float4*)src;     // raw; converted later (CONV)
                fA1 = *(const float4*)(src+4);
            } else {
                #pragma unroll
                for (int i=0;i<8;i++){ rah[i]=(f16)0; ral[i]=(f16)0; }
            }
        }
    };
    auto CONV = [&](int k0){     // MODE 1: mirror LOAD's branch, convert SR floats
        int kk = k0 + seg*8;
        int kabs = kbase + kk;
        if (kabs >= 144 && kabs < 6288){
            float fv[8]={fA0.x,fA0.y,fA0.z,fA0.w,fA1.x,fA1.y,fA1.z,fA1.w};
            #pragma unroll
            for (int i=0;i<8;i++){
                f16 h=(f16)fv[i];
                rah[i]=h; ral[i]=(f16)(fv[i]-(float)h);
            }
        }
    };

    LOAD(0);
    if (MODE==1) CONV(0);
    int lane = t&63, wv = t>>6;
    int lrow = lane&15, quad = lane>>4;
    floatx4 acc[NT/16] = {};
    int cur = 0;
    for (int it=0; it<nIter; ++it){
        *(half8*)&Ash[cur][r][seg*8] = rah;
        *(half8*)&Asl[cur][r][seg*8] = ral;
        if (ldB){
            *(half8*)&Bsh[cur][r][seg*8] = rbh;
            *(half8*)&Bsl[cur][r][seg*8] = rbl;
        }
        if (it+1 < nIter) LOAD((it+1)<<5);
        // wait only LDS writes; raw barrier does NOT drain vmcnt -> prefetch stays in flight
        asm volatile("s_waitcnt lgkmcnt(0)" ::: "memory");
        __builtin_amdgcn_s_barrier();
        half8 ah = *(const half8*)&Ash[cur][wv*16+lrow][quad*8];
        half8 al = *(const half8*)&Asl[cur][wv*16+lrow][quad*8];
        #pragma unroll
        for (int j=0;j<NT/16;j++){
            half8 bh = *(const half8*)&Bsh[cur][j*16+lrow][quad*8];
            half8 bl = *(const half8*)&Bsl[cur][j*16+lrow][quad*8];
            acc[j] = __builtin_amdgcn_mfma_f32_16x16x32_f16(ah, bh, acc[j], 0,0,0);
            acc[j] = __builtin_amdgcn_mfma_f32_16x16x32_f16(al, bh, acc[j], 0,0,0);
            acc[j] = __builtin_amdgcn_mfma_f32_16x16x32_f16(ah, bl, acc[j], 0,0,0);
        }
        if (MODE==1 && it+1 < nIter) CONV((it+1)<<5);
        cur ^= 1;
    }
    float* Cz = Cc + (size_t)z*cstride;
    #pragma unroll
    for (int j=0;j<NT/16;j++){
        int col = n0 + j*16 + lrow;
        if (col >= Nvalid) continue;
        float bv = bias ? bias[col] : 0.f;
        #pragma unroll
        for (int i=0;i<4;i++){
            int row = m0 + wv*16 + quad*4 + i;
            if (row < M) Cz[(size_t)row*ldc + col] = acc[j][i] + bv;
        }
    }
}

// ================= setup kernels =================

__global__ void k_bt_build(const float* __restrict__ src, f16* __restrict__ hi, f16* __restrict__ lo,
                           int Ksrc, int Nsrc, int ld_src, int NB, int KB, float scale){
    __shared__ float tile[32][33];
    int k0 = blockIdx.x*32, n0 = blockIdx.y*32;
    int lx = threadIdx.x & 31, ly = threadIdx.x >> 5;
    for (int rr=0; rr<32; rr+=8){
        int k2 = k0+ly+rr, n = n0+lx;
        tile[ly+rr][lx] = (k2<Ksrc && n<Nsrc)? src[(size_t)k2*ld_src+n]*scale : 0.f;
    }
    __syncthreads();
    for (int rr=0; rr<32; rr+=8){
        int n = n0+ly+rr, k2 = k0+lx;
        if (n<NB && k2<KB){
            float v = tile[lx][ly+rr];
            f16 h=(f16)v;
            hi[(size_t)n*KB+k2]=h;
            lo[(size_t)n*KB+k2]=(f16)(v-(float)h);
        }
    }
}

__global__ void k_permrows(const float* __restrict__ src, f16* __restrict__ hi, f16* __restrict__ lo,
                           int src_ld, int dst_ld, int kvalid){
    int idx = blockIdx.x*256+threadIdx.x;
    if (idx >= G4H*dst_ld) return;
    int p = idx/dst_ld, k2 = idx%dst_ld;
    int j = p>>2, g = p&3, gi = (g<<9)|j;
    float v = (k2<kvalid)? src[(size_t)gi*src_ld + k2] : 0.f;
    f16 h=(f16)v;
    hi[idx]=h; lo[idx]=(f16)(v-(float)h);
}

__global__ void k_cvt(const float* __restrict__ src, f16* __restrict__ hi, f16* __restrict__ lo,
                      int M, int ld_src, int nvalid, int ld_dst, float scale){
    int idx = blockIdx.x*256+threadIdx.x;
    if (idx >= M*ld_dst) return;
    int m = idx/ld_dst, n = idx%ld_dst;
    float v = (n<nvalid)? src[(size_t)m*ld_src+n]*scale : 0.f;
    f16 h=(f16)v; hi[idx]=h; lo[idx]=(f16)(v-(float)h);
}

__global__ void k_cvtY(const float* __restrict__ Y, f16* __restrict__ hi, f16* __restrict__ lo){
    int idx = blockIdx.x*256+threadIdx.x;
    if (idx >= B*144) return;
    int b = idx/144, k2 = idx%144;
    float v = Y[((size_t)(k2/C)*B + b)*C + (k2%C)];
    f16 h=(f16)v; hi[idx]=h; lo[idx]=(f16)(v-(float)h);
}

__global__ void k_zeroh(f16* a, f16* b2, int n){
    int i = blockIdx.x*256+threadIdx.x; if (i<n){ a[i]=(f16)0; b2[i]=(f16)0; }
}

__global__ void k_prep(const float* __restrict__ bih, const float* __restrict__ bhh,
                       const float* __restrict__ bp, const float* __restrict__ Wih,
                       float* __restrict__ bias2p, float* __restrict__ biascat,
                       float* __restrict__ wl){
    int i = blockIdx.x*256 + threadIdx.x;
    if (i < G4H){
        int g=i&3, j=i>>2; int gi=(g<<9)|j;
        bias2p[i]=bih[gi]+bhh[gi];
        wl[i]=Wih[(size_t)gi*DP1 + 1024];
    }
    if (i < C) biascat[i]=bp[i];
}

__global__ void k_cls(const float* __restrict__ S, const float* __restrict__ R,
                      const float* __restrict__ clsW, const float* __restrict__ clsb,
                      float* __restrict__ Y){
    int kb = blockIdx.x; int k = kb / B; int b = kb % B;
    int t = threadIdx.x; // 64
    __shared__ float sr[64];
    __shared__ float lg[C];
    __shared__ float mred[2];
    float acc = (t<C) ? clsb[k*C+t] : 0.f;
    const float* W = clsW + (size_t)k*2*D*C;
    for (int i0=0; i0<2*D; i0+=64){
        int i = i0 + t;
        sr[t] = (i < D) ? S[((size_t)k*B+b)*D + i] : R[((size_t)k*B+b)*D + (i-D)];
        __syncthreads();
        if (t < C){ for (int ii=0; ii<64; ++ii) acc += sr[ii]*W[(size_t)(i0+ii)*C + t]; }
        __syncthreads();
    }
    if (t<C) lg[t]=acc;
    __syncthreads();
    if (t==0){
        float m=lg[0]; for(int c2=1;c2<C;c2++) m=fmaxf(m,lg[c2]);
        float s=0.f; for(int c2=0;c2<C;c2++) s+=expf(lg[c2]-m);
        mred[0]=m; mred[1]=s;
    }
    __syncthreads();
    if (t<C) Y[((size_t)k*B+b)*C + t] = expf(lg[t]-mred[0])/mred[1];
}

__global__ void k_curr_action(const float* __restrict__ Y, float* __restrict__ outca){
    int i = blockIdx.x*256+threadIdx.x; if (i>=B*C) return;
    int b=i/C, c2=i%C;
    outca[i] = Y[((size_t)0*B+b)*C+c2] + Y[((size_t)1*B+b)*C+c2] + Y[((size_t)2*B+b)*C+c2];
}

__global__ void k_dur0(const float* __restrict__ R, const float* __restrict__ durW,
                       const float* __restrict__ durb, float* __restrict__ outpad){
    int b = blockIdx.x; int t = threadIdx.x;
    __shared__ float red[256];
    float p=0.f;
    for (int i=t; i<K*D; i+=256){ int k=i>>10, d=i&1023; p += R[((size_t)k*B+b)*D+d]*durW[i]; }
    red[t]=p; __syncthreads();
    for (int s=128;s>0;s>>=1){ if(t<s) red[t]+=red[t+s]; __syncthreads(); }
    if (t==0) outpad[(size_t)b*(T+1)] = red[0] + durb[0];
}

__global__ void k_red(float* __restrict__ dst, const float* __restrict__ src, int parts, size_t pstride,
                      int M, int Nld, int Nvalid, const float* __restrict__ bias){
    int idx = blockIdx.x*256+threadIdx.x;
    if (idx >= M*Nld) return;
    int n = idx % Nld;
    float v = 0.f;
    if (n < Nvalid){
        for (int p=0;p<parts;p++) v += src[(size_t)p*pstride + idx];
        if (bias) v += bias[n];
    }
    dst[idx]=v;
}

__global__ void k_redcvt(const float* __restrict__ src, int parts, size_t pstride,
                         const float* __restrict__ bias, f16* __restrict__ hi, f16* __restrict__ lo){
    int idx = blockIdx.x*256+threadIdx.x;
    if (idx >= 512*KP) return;
    int m = idx/KP, n = idx%KP;
    float v = 0.f;
    if (n < DP1){
        for (int p=0;p<parts;p++) v += src[(size_t)p*pstride + (size_t)m*1028 + n];
        v += bias[n];
    }
    f16 h=(f16)v; hi[idx]=h; lo[idx]=(f16)(v-(float)h);
}

// ================= scan kernels =================

// fused split-K reduce + bias + LSTM step 0
__global__ void k_lstm0(const float* __restrict__ gxp, int parts, size_t pstride,
                        const float* __restrict__ bias2p,
                        float* __restrict__ c, f16* __restrict__ hhi, f16* __restrict__ hlo){
    int idx = blockIdx.x*256+threadIdx.x; if (idx>=B*H) return;
    int r=idx>>9, j=idx&511;
    float4 g = *(const float4*)&gxp[(size_t)r*G4H + (j<<2)];
    if (parts==2){
        float4 g2 = *(const float4*)&gxp[pstride + (size_t)r*G4H + (j<<2)];
        g.x+=g2.x; g.y+=g2.y; g.z+=g2.z; g.w+=g2.w;
    }
    float4 bb = *(const float4*)&bias2p[j<<2];
    g.x+=bb.x; g.y+=bb.y; g.z+=bb.z; g.w+=bb.w;
    float cn = sigf(g.x)*tanhf_fast(g.z);
    c[idx]=cn;
    float hv = sigf(g.w)*tanhf_fast(cn);
    f16 h=(f16)hv; hhi[idx]=h; hlo[idx]=(f16)(hv-(float)h);
}

// barrier-free per-row postapply: ONE 64-lane wave owns one batch row end-to-end.
// All reductions are shfl_xor butterflies (result lands in every lane -> no LDS, no
// __syncthreads, no broadcast). 512 independent latency chains across the device.
template<int PARTS>
__global__ __launch_bounds__(64)
void k_postwave(const float* __restrict__ rawg, size_t pstride,
                const float* __restrict__ S, const float* __restrict__ V,
                const f16* __restrict__ hchi, const f16* __restrict__ hclo,
                const f16* __restrict__ holdhi, const f16* __restrict__ holdlo,
                const float* __restrict__ E, const float* __restrict__ wl,
                const float* __restrict__ biascat,
                const float* __restrict__ Wdur, const float* __restrict__ bdur,
                float* __restrict__ outlab, float* __restrict__ outprobs,
                float* __restrict__ outatt, float* __restrict__ outpad,
                float* __restrict__ c, f16* __restrict__ hNhi, f16* __restrict__ hNlo,
                int tstep, int doLstm)
{
    const int b = blockIdx.x, lane = threadIdx.x;
    const float* z0 = rawg + (size_t)b*NC;

    // ---- issue the attention-score loads early (independent of logits) ----
    float hv8[8], va0[8], va1[8], va2[8];
    {
        half8 hh = *(const half8*)(hchi + (size_t)b*H + lane*8);
        half8 hl = *(const half8*)(hclo + (size_t)b*H + lane*8);
        #pragma unroll
        for (int i=0;i<8;i++) hv8[i] = (float)hh[i] + (float)hl[i];
        const float* V0 = V + ((size_t)(0*B+b))*H + lane*8;
        const float* V1 = V + ((size_t)(1*B+b))*H + lane*8;
        const float* V2 = V + ((size_t)(2*B+b))*H + lane*8;
        *(float4*)va0 = *(const float4*)V0; *(float4*)(va0+4) = *(const float4*)(V0+4);
        *(float4*)va1 = *(const float4*)V1; *(float4*)(va1+4) = *(const float4*)(V1+4);
        *(float4*)va2 = *(const float4*)V2; *(float4*)(va2+4) = *(const float4*)(V2+4);
    }

    // ---- logits softmax/argmax (lanes 0..47 hold values; butterfly leaves result in all lanes) ----
    float lgv = -3.0e38f;
    if (lane < C){
        float v = 0.f;
        #pragma unroll
        for (int p=0;p<PARTS;p++) v += z0[(size_t)p*pstride + G4H + lane];
        lgv = v + biascat[lane];
    }
    float m = lgv; int bi = lane;
    #pragma unroll
    for (int s2=32;s2>0;s2>>=1){
        float om = __shfl_xor(m, s2); int ob = __shfl_xor(bi, s2);
        if (om>m || (om==m && ob<bi)){ m=om; bi=ob; }
    }
    float e = (lane<C)? __expf(lgv-m) : 0.f;
    float ss = e;
    #pragma unroll
    for (int s2=32;s2>0;s2>>=1) ss += __shfl_xor(ss, s2);
    if (lane<C) outprobs[(size_t)b*(T*C)+tstep*C+lane] = e/ss;
    if (lane==0) outlab[(size_t)tstep*B+b] = (float)bi;

    // ---- attention scores p_k = h . V[k,b,:] ----
    float p0=0.f,p1=0.f,p2=0.f;
    #pragma unroll
    for (int i=0;i<8;i++){ p0 += hv8[i]*va0[i]; p1 += hv8[i]*va1[i]; p2 += hv8[i]*va2[i]; }
    #pragma unroll
    for (int s2=32;s2>0;s2>>=1){
        p0 += __shfl_xor(p0,s2); p1 += __shfl_xor(p1,s2); p2 += __shfl_xor(p2,s2);
    }
    float m3 = fmaxf(p0,fmaxf(p1,p2));
    float e0 = __expf(p0-m3), e1 = __expf(p1-m3), e2 = __expf(p2-m3);
    float si = 1.f/(e0+e1+e2);
    float a0=e0*si, a1=e1*si, a2=e2*si;

    // ---- attention output + dur head ----
    const float* S0  = S + (size_t)b*D;
    const float* S1  = S0 + (size_t)B*D;
    const float* S2p = S1 + (size_t)B*D;
    float* attp = outatt + (size_t)tstep*B*D + (size_t)b*D;
    float dp = 0.f;
    #pragma unroll
    for (int i=0;i<4;i++){
        int d = (lane + (i<<6))<<2;
        float4 s0 = *(const float4*)(S0+d);
        float4 s1 = *(const float4*)(S1+d);
        float4 s2 = *(const float4*)(S2p+d);
        float4 w4 = *(const float4*)(Wdur+d);
        float4 av;
        av.x = a0*s0.x+a1*s1.x+a2*s2.x;
        av.y = a0*s0.y+a1*s1.y+a2*s2.y;
        av.z = a0*s0.z+a1*s1.z+a2*s2.z;
        av.w = a0*s0.w+a1*s1.w+a2*s2.w;
        *(float4*)(attp+d) = av;
        dp += av.x*w4.x+av.y*w4.y+av.z*w4.z+av.w*w4.w;
    }
    if (holdhi){
        half8 oh = *(const half8*)(holdhi + (size_t)b*H + lane*8);
        half8 ol = *(const half8*)(holdlo + (size_t)b*H + lane*8);
        const float* wd = Wdur + D + lane*8;
        float w8[8];
        *(float4*)w8 = *(const float4*)wd; *(float4*)(w8+4) = *(const float4*)(wd+4);
        #pragma unroll
        for (int i=0;i<8;i++) dp += ((float)oh[i]+(float)ol[i]) * w8[i];
    }
    #pragma unroll
    for (int s2=32;s2>0;s2>>=1) dp += __shfl_xor(dp,s2);
    float dv = dp + bdur[0];
    if (lane==0) outpad[(size_t)b*(T+1)+tstep+1] = dv;

    // ---- LSTM cell (next h) ----
    if (doLstm){
        const float* Erow = E + (size_t)bi*G4H;
        #pragma unroll
        for (int i=0;i<8;i++){
            int j = lane + (i<<6);
            float4 g4 = *(const float4*)(z0 + 4*j);
            #pragma unroll
            for (int p=1;p<PARTS;p++){
                float4 h4 = *(const float4*)(z0 + (size_t)p*pstride + 4*j);
                g4.x+=h4.x; g4.y+=h4.y; g4.z+=h4.z; g4.w+=h4.w;
            }
            float4 e4 = *(const float4*)(Erow + 4*j);
            float4 w4 = *(const float4*)(wl + 4*j);
            float gi = g4.x+e4.x+dv*w4.x;
            float gf = g4.y+e4.y+dv*w4.y;
            float gg = g4.z+e4.z+dv*w4.z;
            float go = g4.w+e4.w+dv*w4.w;
            size_t ci = (size_t)b*H+j;
            float cn = sigf(gf)*c[ci] + sigf(gi)*tanhf_fast(gg);
            c[ci] = cn;
            float hv = sigf(go)*tanhf_fast(cn);
            f16 hh = (f16)hv;
            hNhi[ci]=hh; hNlo[ci]=(f16)(hv-(float)hh);
        }
    }
}

// ================= host =================

extern "C" void kernel_launch(void* const* d_in, const int* in_sizes, int n_in,
                              void* d_out, int out_size, void* d_ws, size_t ws_size,
                              hipStream_t stream) {
    const float* S    = (const float*)d_in[0];
    const float* R    = (const float*)d_in[1];
    const float* clsW = (const float*)d_in[2];
    const float* clsb = (const float*)d_in[3];
    const float* durW = (const float*)d_in[4];
    const float* durb = (const float*)d_in[5];
    const float* linW = (const float*)d_in[6];
    const float* linb = (const float*)d_in[7];
    const float* Wih  = (const float*)d_in[8];
    const float* Whh  = (const float*)d_in[9];
    const float* bih  = (const float*)d_in[10];
    const float* bhh  = (const float*)d_in[11];
    const float* Wp   = (const float*)d_in[12];
    const float* bp   = (const float*)d_in[13];
    const float* Wdur = (const float*)d_in[14];
    const float* bdur = (const float*)d_in[15];
    const float* embed= (const float*)d_in[16];
    const float* Wattn= (const float*)d_in[17];

    float* out = (float*)d_out;
    float* outlab   = out;                 // [T,B]
    float* outprobs = out + 12800;         // [B,T,C]
    float* outca    = out + 627200;        // [B,C]
    float* outpad   = out + 651776;        // [B,T+1]
    float* outatt   = out + 665088;        // [T,B,D]

    float* ws = (float*)d_ws;
    // persistent block
    float* E       = ws + 0;               // 98,304
    float* wl      = ws + 98304;           // 2,048
    float* bias2p  = ws + 100352;          // 2,048
    float* biascat = ws + 102400;          // 64
    float* c       = ws + 102464;          // 262,144
    f16*   hAhi    = (f16*)(ws + 364608);  // 262,144 f16
    f16*   hAlo    = (f16*)(ws + 495680);
    f16*   hBhi    = (f16*)(ws + 626752);
    f16*   hBlo    = (f16*)(ws + 757824);
    f16*   Yhi     = (f16*)(ws + 889920);  // 512*144 f16
    f16*   Ylo     = (f16*)(ws + 926784);
    float* Y       = ws + 963648;          // 73,728 -> ends 1,037,376
    f16*   watthi  = (f16*)(ws + 1037376); // 512*1024 f16 = 262,144 fl
    f16*   wattlo  = (f16*)(ws + 1299520); // ends 1,561,664 < 1,563,712
    f16*   x0hi    = (f16*)(ws + 1563712); // 512*1056 f16
    f16*   x0lo    = (f16*)(ws + 1834048);
    f16*   embhi   = (f16*)(ws + 2104384); // 48*1056 f16
    f16*   emblo   = (f16*)(ws + 2129728);
    // big scratch region, time-multiplexed (within the 40.26 MB floor):
    //  stage1 (x0): linWt hi/lo [SB .. SB+6,858,752) + x0part [SB+6,858,752 ..)
    //  stage2: Wct2 | S hi/lo | V | Wihp (setup) / rawg 2-parts (scan, overlays dead Wihp)
    //          gpart (gx0/E partials) after Wihp.
    const size_t SB = 2155072;
    f16*   lwthi   = (f16*)(ws + SB);               // 1088*6304 f16
    f16*   lwtlo   = (f16*)(ws + SB + 3429376);
    float* x0part  = ws + SB + 6858752;             // ZX0*512*1028 (ws-gated)
    f16*   Wcthi   = (f16*)(ws + SB);               // 2112*512 f16 = 540,672 fl
    f16*   Wctlo   = (f16*)(ws + SB + 540672);      // ends SB+1,081,344
    f16*   Shi     = (f16*)(ws + SB + 1081344);     // 1536*1024 f16 = 786,432 fl
    f16*   Slo     = (f16*)(ws + SB + 1867776);     // ends SB+2,654,208
    float* Vbuf    = ws + SB + 2654208;             // 786,432 fl, ends SB+3,440,640
    f16*   Wihphi  = (f16*)(ws + SB + 3440640);     // 2048*1056 f16 = 1,081,344 fl (setup only)
    f16*   Wihplo  = (f16*)(ws + SB + 4521984);     // ends SB+5,603,328
    float* rawg    = ws + SB + 3440640;             // scan only: 2*512*2112 = 2,162,688 fl (overlays dead Wihp)
    float* gpart   = ws + SB + 5603328;             // setup partials (gx0: 2*512*2048, E: 4*48*2048)

    // ---- workspace-gated split-K config for x0 ----
    int ZX0, ksl_x0;
    if      (ws_size >= (size_t)52898048){ ZX0=8; ksl_x0=800;  }
    else if (ws_size >= (size_t)44476672){ ZX0=4; ksl_x0=1600; }
    else                                 { ZX0=2; ksl_x0=3168; }
    const int ZGX = 2, ksl_gx = 544;
    const int ZE  = 4, ksl_e  = 256;
    const int ZSC = 2, ksl_sc = 256;    // scan split-K: 2 (r7-measured best)

    // ---- setup ----
    k_prep<<<8,256,0,stream>>>(bih,bhh,bp,Wih,bias2p,biascat,wl);
    k_cls<<<K*B,64,0,stream>>>(S,R,clsW,clsb,Y);
    k_curr_action<<<(B*C+255)/256,256,0,stream>>>(Y,outca);
    k_cvtY<<<(B*144+255)/256,256,0,stream>>>(Y,Yhi,Ylo);
    k_dur0<<<B,256,0,stream>>>(R,durW,durb,outpad);
    // linW -> transposed hi/lo [1088][6304]
    k_bt_build<<<dim3((FK+31)/32,(1088+31)/32),256,0,stream>>>(linW,lwthi,lwtlo,6288,1025,1025,1088,FK,1.f);
    // x0 = feat @ linW  (A gathered from Y/S/R, split-K ZX0, z-major, NT=32)
    k_gemm<32,1><<<8*33*ZX0,256,0,stream>>>(nullptr,nullptr,lwthi,lwtlo,x0part,nullptr,
                                            512,1028,FK,0,FK,1028,ksl_x0,(size_t)512*1028,8,ZX0,1,
                                            Yhi,Ylo,S,R);
    k_redcvt<<<(512*KP+255)/256,256,0,stream>>>(x0part,ZX0,(size_t)512*1028,linb,x0hi,x0lo);
    // Wih^T (gate-perm rows) hi/lo   [lwt region is dead from here]
    k_permrows<<<(G4H*KP+255)/256,256,0,stream>>>(Wih,Wihphi,Wihplo,DP1,KP,DP1);
    // gx0 = x0 @ WihT (split-K ZGX, partials in gpart)
    k_gemm<64,0><<<8*32*ZGX,256,0,stream>>>(x0hi,x0lo,Wihphi,Wihplo,gpart,nullptr,
                                            512,G4H,KP,KP,KP,G4H,ksl_gx,(size_t)512*G4H,8,ZGX,0,
                                            nullptr,nullptr,nullptr,nullptr);
    k_lstm0<<<(B*H+255)/256,256,0,stream>>>(gpart,ZGX,(size_t)512*G4H,bias2p,c,hAhi,hAlo);
    k_cvt<<<(48*KP+255)/256,256,0,stream>>>(embed,embhi,emblo,48,1024,1024,KP,1.f);
    // E = embed @ WihT + bias2p (partials reuse gpart after k_lstm0)
    k_gemm<64,0><<<1*32*ZE,256,0,stream>>>(embhi,emblo,Wihphi,Wihplo,gpart,nullptr,
                                           48,G4H,KP,KP,KP,G4H,ksl_e,(size_t)48*G4H,1,ZE,0,
                                           nullptr,nullptr,nullptr,nullptr);
    k_red<<<(48*G4H+255)/256,256,0,stream>>>(E,gpart,ZE,(size_t)48*G4H,48,G4H,G4H,bias2p);
    // V[k,b,:] = (S_k @ Wattn^T)/32  -- removes q (1024 cols) from the step GEMM
    k_cvt<<<(1536*1024+255)/256,256,0,stream>>>(S,Shi,Slo,1536,1024,1024,1024,1.f);
    k_cvt<<<(512*1024+255)/256,256,0,stream>>>(Wattn,watthi,wattlo,512,1024,1024,1024,0.03125f);
    k_gemm<64,0><<<24*8,256,0,stream>>>(Shi,Slo,watthi,wattlo,Vbuf,nullptr,
                                        1536,512,1024,1024,1024,512,1024,0,24,1,0,
                                        nullptr,nullptr,nullptr,nullptr);
    // Wct2 [2112][512]: rows 0..2047 Whh perm | 2048..2095 Wp^T | 2096..2111 pad 0
    k_permrows<<<(G4H*512+255)/256,256,0,stream>>>(Whh,Wcthi,Wctlo,H,H,H);
    k_bt_build<<<dim3(16,2),256,0,stream>>>(Wp,Wcthi+(size_t)2048*512,Wctlo+(size_t)2048*512,
                                            512,48,48,48,512,1.f);
    k_zeroh<<<32,256,0,stream>>>(Wcthi+(size_t)2096*512,Wctlo+(size_t)2096*512,16*512);

    // ---- scan (GEMM: NT=32, ZSC=2 -> 1056 blocks ~4/CU; postapply: 1 wave/row, barrier-free) ----
    size_t pstr = (size_t)512*NC;
    f16 *hCurHi=hAhi, *hCurLo=hAlo, *hPrvHi=hBhi, *hPrvLo=hBlo;
    for (int t=0;t<T;t++){
        k_gemm<32,0><<<8*66*ZSC,256,0,stream>>>(hCurHi,hCurLo,Wcthi,Wctlo,rawg,nullptr,
                                                512,NCV,H,H,H,NC,ksl_sc,pstr,8,ZSC,0,
                                                nullptr,nullptr,nullptr,nullptr);
        k_postwave<2><<<B,64,0,stream>>>(rawg,pstr,S,Vbuf,hCurHi,hCurLo,
                                         (t==0)?nullptr:hPrvHi,(t==0)?nullptr:hPrvLo,
                                         E,wl,biascat,Wdur,bdur,
                                         outlab,outprobs,outatt,outpad,
                                         c,hPrvHi,hPrvLo,t,(t<T-1)?1:0);
        f16* th=hPrvHi; hPrvHi=hCurHi; hCurHi=th;
        f16* tl=hPrvLo; hPrvLo=hCurLo; hCurLo=tl;
    }
}

// Round 10
// 884.219 us; speedup vs baseline: 1.0375x; 1.0375x over previous
//
#include <hip/hip_runtime.h>
#include <math.h>

#define B 512
#define D 1024
#define H 512
#define C 48
#define K 3
#define T 25
#define DP1 1025
#define G4H 2048
#define NC 2112         // step GEMM N (padded): 2048 gates | 48 logits | 16 pad
#define NCV 2096        // valid cols
#define KP 1056         // padded K for x0/embed rows (multiple of 32)

typedef _Float16 f16;
typedef _Float16 half8 __attribute__((ext_vector_type(8)));
typedef float floatx4 __attribute__((ext_vector_type(4)));

__device__ __forceinline__ float sigf(float x){ return 1.0f/(1.0f+__expf(-x)); }
// NaN-safe fast tanh: tanh(x) = sign(x)*(1-t)/(1+t), t=exp(-2|x|) in (0,1]
__device__ __forceinline__ float tanhf_fast(float x){
    float t = __expf(-2.0f*fabsf(x));
    float r = (1.0f-t)/(1.0f+t);
    return x<0.f ? -r : r;
}

// ================= unified split-f16 MFMA GEMM =================
// template<NT, MODE>: NT = n-tile (32/64); MODE 0 = plain A [M][lda] hi/lo;
// MODE 1 = pure-f16 gather A: k<kyoff from Y [m][144]; kyoff<=k<kval from X (3x[512][1024]
// blocks, pre-converted hi/lo); k>=kval zeros. NO in-loop conversion (r8 lesson: redundant
// per-nblk f32->f16 split was ~21us of VALU).
// Counted-vmcnt pipeline: raw s_barrier + lgkmcnt-only wait -> next-tile global prefetch
// stays in flight across the barrier (T3/T4).
template<int NT, int MODE>
__global__ __launch_bounds__(256)
void k_gemm(const f16* __restrict__ Ahi, const f16* __restrict__ Alo,
            const f16* __restrict__ Bhi, const f16* __restrict__ Blo,
            float* __restrict__ Cc, const float* __restrict__ bias,
            int M, int Nvalid, int Ktot, int lda, int ldb, int ldc,
            int ksl, size_t cstride, int MB, int Z, int accu,
            const f16* __restrict__ Yh, const f16* __restrict__ Yl,
            const f16* __restrict__ Xh, const f16* __restrict__ Xl,
            int kyoff, int kval)
{
    __shared__ __align__(16) f16 Ash[2][64][40];
    __shared__ __align__(16) f16 Asl[2][64][40];
    __shared__ __align__(16) f16 Bsh[2][NT][40];
    __shared__ __align__(16) f16 Bsl[2][NT][40];
    int t = threadIdx.x;
    // n-chunked XCD swizzle: same-XCD blocks share an n-range (requires gridDim %8==0)
    int chunk = gridDim.x >> 3;
    int g = (blockIdx.x & 7)*chunk + (blockIdx.x >> 3);
    int mz = g % (MB*Z);
    int nblk = g / (MB*Z);
    int mblk = mz / Z;
    int z    = mz % Z;
    int m0 = mblk*64, n0 = nblk*NT;
    int kbase = z*ksl;
    int kcnt = (z==Z-1)? (Ktot-kbase) : ksl;
    int nIter = kcnt >> 5;
    int r = t>>2, seg = t&3;
    const bool ldB = (r < NT);
    half8 rah, ral, rbh, rbl;

    auto LOAD = [&](int k0){
        int kk = k0 + seg*8;
        if (ldB){
            size_t off = (size_t)(n0+r)*ldb + kbase + kk;
            rbh = *(const half8*)(Bhi + off);
            rbl = *(const half8*)(Blo + off);
        }
        int m = m0 + r;
        if (MODE==0){
            if (m < M){
                size_t off = (size_t)m*lda + kbase + kk;
                rah = *(const half8*)(Ahi + off);
                ral = *(const half8*)(Alo + off);
            } else {
                #pragma unroll
                for (int i=0;i<8;i++){ rah[i]=(f16)0; ral[i]=(f16)0; }
            }
        } else {
            int kabs = kbase + kk;   // 8-aligned; source runs never straddle boundaries
            if (kabs < kyoff){
                rah = *(const half8*)(Yh + (size_t)m*144 + kabs);
                ral = *(const half8*)(Yl + (size_t)m*144 + kabs);
            } else if (kabs < kval){
                int kp = kabs - kyoff;
                size_t off = (size_t)(kp>>10)*((size_t)B*D) + (size_t)m*D + (kp&(D-1));
                rah = *(const half8*)(Xh + off);
                ral = *(const half8*)(Xl + off);
            } else {
                #pragma unroll
                for (int i=0;i<8;i++){ rah[i]=(f16)0; ral[i]=(f16)0; }
            }
        }
    };

    LOAD(0);
    int lane = t&63, wv = t>>6;
    int lrow = lane&15, quad = lane>>4;
    floatx4 acc[NT/16] = {};
    int cur = 0;
    for (int it=0; it<nIter; ++it){
        *(half8*)&Ash[cur][r][seg*8] = rah;
        *(half8*)&Asl[cur][r][seg*8] = ral;
        if (ldB){
            *(half8*)&Bsh[cur][r][seg*8] = rbh;
            *(half8*)&Bsl[cur][r][seg*8] = rbl;
        }
        if (it+1 < nIter) LOAD((it+1)<<5);
        // wait only LDS writes; raw barrier does NOT drain vmcnt -> prefetch stays in flight
        asm volatile("s_waitcnt lgkmcnt(0)" ::: "memory");
        __builtin_amdgcn_s_barrier();
        half8 ah = *(const half8*)&Ash[cur][wv*16+lrow][quad*8];
        half8 al = *(const half8*)&Asl[cur][wv*16+lrow][quad*8];
        #pragma unroll
        for (int j=0;j<NT/16;j++){
            half8 bh = *(const half8*)&Bsh[cur][j*16+lrow][quad*8];
            half8 bl = *(const half8*)&Bsl[cur][j*16+lrow][quad*8];
            acc[j] = __builtin_amdgcn_mfma_f32_16x16x32_f16(ah, bh, acc[j], 0,0,0);
            acc[j] = __builtin_amdgcn_mfma_f32_16x16x32_f16(al, bh, acc[j], 0,0,0);
            acc[j] = __builtin_amdgcn_mfma_f32_16x16x32_f16(ah, bl, acc[j], 0,0,0);
        }
        cur ^= 1;
    }
    float* Cz = Cc + (size_t)z*cstride;
    #pragma unroll
    for (int j=0;j<NT/16;j++){
        int col = n0 + j*16 + lrow;
        if (col >= Nvalid) continue;
        float bv = bias ? bias[col] : 0.f;
        #pragma unroll
        for (int i=0;i<4;i++){
            int row = m0 + wv*16 + quad*4 + i;
            if (row < M){
                size_t idx = (size_t)row*ldc + col;
                if (accu) Cz[idx] += acc[j][i];
                else      Cz[idx]  = acc[j][i] + bv;
            }
        }
    }
}

// ================= setup kernels =================

__global__ void k_bt_build(const float* __restrict__ src, f16* __restrict__ hi, f16* __restrict__ lo,
                           int Ksrc, int Nsrc, int ld_src, int NB, int KB, float scale){
    __shared__ float tile[32][33];
    int k0 = blockIdx.x*32, n0 = blockIdx.y*32;
    int lx = threadIdx.x & 31, ly = threadIdx.x >> 5;
    for (int rr=0; rr<32; rr+=8){
        int k2 = k0+ly+rr, n = n0+lx;
        tile[ly+rr][lx] = (k2<Ksrc && n<Nsrc)? src[(size_t)k2*ld_src+n]*scale : 0.f;
    }
    __syncthreads();
    for (int rr=0; rr<32; rr+=8){
        int n = n0+ly+rr, k2 = k0+lx;
        if (n<NB && k2<KB){
            float v = tile[lx][ly+rr];
            f16 h=(f16)v;
            hi[(size_t)n*KB+k2]=h;
            lo[(size_t)n*KB+k2]=(f16)(v-(float)h);
        }
    }
}

__global__ void k_permrows(const float* __restrict__ src, f16* __restrict__ hi, f16* __restrict__ lo,
                           int src_ld, int dst_ld, int kvalid){
    int idx = blockIdx.x*256+threadIdx.x;
    if (idx >= G4H*dst_ld) return;
    int p = idx/dst_ld, k2 = idx%dst_ld;
    int j = p>>2, g = p&3, gi = (g<<9)|j;
    float v = (k2<kvalid)? src[(size_t)gi*src_ld + k2] : 0.f;
    f16 h=(f16)v;
    hi[idx]=h; lo[idx]=(f16)(v-(float)h);
}

__global__ void k_cvt(const float* __restrict__ src, f16* __restrict__ hi, f16* __restrict__ lo,
                      int M, int ld_src, int nvalid, int ld_dst, float scale){
    int idx = blockIdx.x*256+threadIdx.x;
    if (idx >= M*ld_dst) return;
    int m = idx/ld_dst, n = idx%ld_dst;
    float v = (n<nvalid)? src[(size_t)m*ld_src+n]*scale : 0.f;
    f16 h=(f16)v; hi[idx]=h; lo[idx]=(f16)(v-(float)h);
}

__global__ void k_cvtY(const float* __restrict__ Y, f16* __restrict__ hi, f16* __restrict__ lo){
    int idx = blockIdx.x*256+threadIdx.x;
    if (idx >= B*144) return;
    int b = idx/144, k2 = idx%144;
    float v = Y[((size_t)(k2/C)*B + b)*C + (k2%C)];
    f16 h=(f16)v; hi[idx]=h; lo[idx]=(f16)(v-(float)h);
}

__global__ void k_zeroh(f16* a, f16* b2, int n){
    int i = blockIdx.x*256+threadIdx.x; if (i<n){ a[i]=(f16)0; b2[i]=(f16)0; }
}

__global__ void k_prep(const float* __restrict__ bih, const float* __restrict__ bhh,
                       const float* __restrict__ bp, const float* __restrict__ Wih,
                       float* __restrict__ bias2p, float* __restrict__ biascat,
                       float* __restrict__ wl){
    int i = blockIdx.x*256 + threadIdx.x;
    if (i < G4H){
        int g=i&3, j=i>>2; int gi=(g<<9)|j;
        bias2p[i]=bih[gi]+bhh[gi];
        wl[i]=Wih[(size_t)gi*DP1 + 1024];
    }
    if (i < C) biascat[i]=bp[i];
}

__global__ void k_cls(const float* __restrict__ S, const float* __restrict__ R,
                      const float* __restrict__ clsW, const float* __restrict__ clsb,
                      float* __restrict__ Y){
    int kb = blockIdx.x; int k = kb / B; int b = kb % B;
    int t = threadIdx.x; // 64
    __shared__ float sr[64];
    __shared__ float lg[C];
    __shared__ float mred[2];
    float acc = (t<C) ? clsb[k*C+t] : 0.f;
    const float* W = clsW + (size_t)k*2*D*C;
    for (int i0=0; i0<2*D; i0+=64){
        int i = i0 + t;
        sr[t] = (i < D) ? S[((size_t)k*B+b)*D + i] : R[((size_t)k*B+b)*D + (i-D)];
        __syncthreads();
        if (t < C){ for (int ii=0; ii<64; ++ii) acc += sr[ii]*W[(size_t)(i0+ii)*C + t]; }
        __syncthreads();
    }
    if (t<C) lg[t]=acc;
    __syncthreads();
    if (t==0){
        float m=lg[0]; for(int c2=1;c2<C;c2++) m=fmaxf(m,lg[c2]);
        float s=0.f; for(int c2=0;c2<C;c2++) s+=expf(lg[c2]-m);
        mred[0]=m; mred[1]=s;
    }
    __syncthreads();
    if (t<C) Y[((size_t)k*B+b)*C + t] = expf(lg[t]-mred[0])/mred[1];
}

__global__ void k_curr_action(const float* __restrict__ Y, float* __restrict__ outca){
    int i = blockIdx.x*256+threadIdx.x; if (i>=B*C) return;
    int b=i/C, c2=i%C;
    outca[i] = Y[((size_t)0*B+b)*C+c2] + Y[((size_t)1*B+b)*C+c2] + Y[((size_t)2*B+b)*C+c2];
}

__global__ void k_dur0(const float* __restrict__ R, const float* __restrict__ durW,
                       const float* __restrict__ durb, float* __restrict__ outpad){
    int b = blockIdx.x; int t = threadIdx.x;
    __shared__ float red[256];
    float p=0.f;
    for (int i=t; i<K*D; i+=256){ int k=i>>10, d=i&1023; p += R[((size_t)k*B+b)*D+d]*durW[i]; }
    red[t]=p; __syncthreads();
    for (int s=128;s>0;s>>=1){ if(t<s) red[t]+=red[t+s]; __syncthreads(); }
    if (t==0) outpad[(size_t)b*(T+1)] = red[0] + durb[0];
}

__global__ void k_red(float* __restrict__ dst, const float* __restrict__ src, int parts, size_t pstride,
                      int M, int Nld, int Nvalid, const float* __restrict__ bias){
    int idx = blockIdx.x*256+threadIdx.x;
    if (idx >= M*Nld) return;
    int n = idx % Nld;
    float v = 0.f;
    if (n < Nvalid){
        for (int p=0;p<parts;p++) v += src[(size_t)p*pstride + idx];
        if (bias) v += bias[n];
    }
    dst[idx]=v;
}

__global__ void k_redcvt(const float* __restrict__ src, int parts, size_t pstride,
                         const float* __restrict__ bias, f16* __restrict__ hi, f16* __restrict__ lo){
    int idx = blockIdx.x*256+threadIdx.x;
    if (idx >= 512*KP) return;
    int m = idx/KP, n = idx%KP;
    float v = 0.f;
    if (n < DP1){
        for (int p=0;p<parts;p++) v += src[(size_t)p*pstride + (size_t)m*1028 + n];
        v += bias[n];
    }
    f16 h=(f16)v; hi[idx]=h; lo[idx]=(f16)(v-(float)h);
}

// ================= scan kernels =================

// fused split-K reduce + bias + LSTM step 0
__global__ void k_lstm0(const float* __restrict__ gxp, int parts, size_t pstride,
                        const float* __restrict__ bias2p,
                        float* __restrict__ c, f16* __restrict__ hhi, f16* __restrict__ hlo){
    int idx = blockIdx.x*256+threadIdx.x; if (idx>=B*H) return;
    int r=idx>>9, j=idx&511;
    float4 g = *(const float4*)&gxp[(size_t)r*G4H + (j<<2)];
    if (parts==2){
        float4 g2 = *(const float4*)&gxp[pstride + (size_t)r*G4H + (j<<2)];
        g.x+=g2.x; g.y+=g2.y; g.z+=g2.z; g.w+=g2.w;
    }
    float4 bb = *(const float4*)&bias2p[j<<2];
    g.x+=bb.x; g.y+=bb.y; g.z+=bb.z; g.w+=bb.w;
    float cn = sigf(g.x)*tanhf_fast(g.z);
    c[idx]=cn;
    float hv = sigf(g.w)*tanhf_fast(cn);
    f16 h=(f16)hv; hhi[idx]=h; hlo[idx]=(f16)(hv-(float)h);
}

// fused: softmax/argmax + probs + attention (via precomputed V) + dur head + LSTM cell.
// 512 threads; wave-shfl reductions; PARTS-way split-K partial sum inline. (r7 config)
template<int PARTS>
__global__ void k_postapply(const float* __restrict__ rawg, size_t pstride,
                       const float* __restrict__ S, const float* __restrict__ V,
                       const f16* __restrict__ hchi, const f16* __restrict__ hclo,
                       const f16* __restrict__ holdhi, const f16* __restrict__ holdlo,
                       const float* __restrict__ E, const float* __restrict__ wl,
                       const float* __restrict__ biascat,
                       const float* __restrict__ Wdur, const float* __restrict__ bdur,
                       float* __restrict__ outlab, float* __restrict__ outprobs,
                       float* __restrict__ outatt, float* __restrict__ outpad,
                       float* __restrict__ c, f16* __restrict__ hNhi, f16* __restrict__ hNlo,
                       int tstep, int doLstm)
{
    int b=blockIdx.x, t=threadIdx.x;
    int lane=t&63, wv=t>>6;
    __shared__ float aw[3];
    __shared__ float redw[4][8];
    __shared__ int sbest;
    __shared__ float sdv;
    const float* z0 = rawg + (size_t)b*NC;
    // logits softmax/argmax on wave 0
    if (t<64){
        float lgv = -3.0e38f;
        if (t<C){
            float v = 0.f;
            #pragma unroll
            for (int p=0;p<PARTS;p++) v += z0[(size_t)p*pstride + G4H + t];
            lgv = v + biascat[t];
        }
        float m = lgv; int bi = t;
        #pragma unroll
        for (int s2=32;s2>0;s2>>=1){
            float om=__shfl_xor(m,s2); int ob=__shfl_xor(bi,s2);
            if (om>m || (om==m && ob<bi)){ m=om; bi=ob; }
        }
        float e=(t<C)? __expf(lgv-m):0.f;
        float ss=e;
        #pragma unroll
        for (int s2=32;s2>0;s2>>=1) ss+=__shfl_xor(ss,s2);
        if (t<C) outprobs[(size_t)b*(T*C)+tstep*C+t]=e/ss;
        if (t==0){
            sbest=bi;
            outlab[(size_t)tstep*B+b]=(float)bi;
        }
    }
    // attention scores via precomputed V: p_k = h . V[k,b,:]
    float hv_t = (float)hchi[(size_t)b*H + t] + (float)hclo[(size_t)b*H + t];
    float p0 = hv_t * V[((size_t)(0*B+b))*H + t];
    float p1 = hv_t * V[((size_t)(1*B+b))*H + t];
    float p2 = hv_t * V[((size_t)(2*B+b))*H + t];
    #pragma unroll
    for (int s2=32;s2>0;s2>>=1){
        p0 += __shfl_xor(p0,s2); p1 += __shfl_xor(p1,s2); p2 += __shfl_xor(p2,s2);
    }
    if (lane==0){ redw[0][wv]=p0; redw[1][wv]=p1; redw[2][wv]=p2; }
    __syncthreads();
    if (t==0){
        float a0=0.f,a1=0.f,a2=0.f;
        #pragma unroll
        for (int w=0;w<8;w++){ a0+=redw[0][w]; a1+=redw[1][w]; a2+=redw[2][w]; }
        float m=fmaxf(a0,fmaxf(a1,a2));
        float e0=__expf(a0-m), e1=__expf(a1-m), e2=__expf(a2-m);
        float si=1.f/(e0+e1+e2);
        aw[0]=e0*si; aw[1]=e1*si; aw[2]=e2*si;
    }
    __syncthreads();
    float a0=aw[0],a1=aw[1],a2=aw[2];
    const float* S0  = S + (size_t)b*D;
    const float* S1  = S0 + (size_t)B*D;
    const float* S2p = S1 + (size_t)B*D;
    float dp = 0.f;
    float* attp = outatt + (size_t)tstep*B*D + (size_t)b*D;
    {
        int d = t<<1;   // single pass: 512 threads x float2 = 1024 floats = D
        float2 s0 = *(const float2*)(S0+d);
        float2 s1 = *(const float2*)(S1+d);
        float2 s2 = *(const float2*)(S2p+d);
        float2 w2 = *(const float2*)(Wdur+d);
        float2 av;
        av.x = a0*s0.x+a1*s1.x+a2*s2.x;
        av.y = a0*s0.y+a1*s1.y+a2*s2.y;
        *(float2*)(attp+d) = av;
        dp += av.x*w2.x+av.y*w2.y;
    }
    if (holdhi){
        float hvo = (float)holdhi[(size_t)b*H+t] + (float)holdlo[(size_t)b*H+t];
        dp += hvo * Wdur[D+t];
    }
    #pragma unroll
    for (int s2=32;s2>0;s2>>=1) dp += __shfl_xor(dp,s2);
    if (lane==0) redw[3][wv]=dp;
    __syncthreads();
    if (t==0){
        float dv=0.f;
        #pragma unroll
        for (int w=0;w<8;w++) dv+=redw[3][w];
        dv += bdur[0];
        outpad[(size_t)b*(T+1)+tstep+1]=dv; sdv=dv;
    }
    __syncthreads();
    if (doLstm){
        int lb=sbest; float dv=sdv;
        int j=t;   // 512 threads == H
        float4 g4 = *(const float4*)&z0[4*j];
        #pragma unroll
        for (int p=1;p<PARTS;p++){
            float4 h4 = *(const float4*)&z0[(size_t)p*pstride + 4*j];
            g4.x+=h4.x; g4.y+=h4.y; g4.z+=h4.z; g4.w+=h4.w;
        }
        float4 e4 = *(const float4*)&E[(size_t)lb*G4H+4*j];
        float4 w4 = *(const float4*)&wl[4*j];
        float gi = g4.x+e4.x+dv*w4.x;
        float gf = g4.y+e4.y+dv*w4.y;
        float gg = g4.z+e4.z+dv*w4.z;
        float go = g4.w+e4.w+dv*w4.w;
        size_t ci=(size_t)b*H+j;
        float cn = sigf(gf)*c[ci] + sigf(gi)*tanhf_fast(gg);
        c[ci]=cn;
        float hv = sigf(go)*tanhf_fast(cn);
        f16 hh=(f16)hv;
        hNhi[ci]=hh; hNlo[ci]=(f16)(hv-(float)hh);
    }
}

// ================= host =================

extern "C" void kernel_launch(void* const* d_in, const int* in_sizes, int n_in,
                              void* d_out, int out_size, void* d_ws, size_t ws_size,
                              hipStream_t stream) {
    const float* S    = (const float*)d_in[0];
    const float* R    = (const float*)d_in[1];
    const float* clsW = (const float*)d_in[2];
    const float* clsb = (const float*)d_in[3];
    const float* durW = (const float*)d_in[4];
    const float* durb = (const float*)d_in[5];
    const float* linW = (const float*)d_in[6];
    const float* linb = (const float*)d_in[7];
    const float* Wih  = (const float*)d_in[8];
    const float* Whh  = (const float*)d_in[9];
    const float* bih  = (const float*)d_in[10];
    const float* bhh  = (const float*)d_in[11];
    const float* Wp   = (const float*)d_in[12];
    const float* bp   = (const float*)d_in[13];
    const float* Wdur = (const float*)d_in[14];
    const float* bdur = (const float*)d_in[15];
    const float* embed= (const float*)d_in[16];
    const float* Wattn= (const float*)d_in[17];

    float* out = (float*)d_out;
    float* outlab   = out;                 // [T,B]
    float* outprobs = out + 12800;         // [B,T,C]
    float* outca    = out + 627200;        // [B,C]
    float* outpad   = out + 651776;        // [B,T+1]
    float* outatt   = out + 665088;        // [T,B,D]

    float* ws = (float*)d_ws;
    // persistent block [0 .. 2,155,072)
    float* E       = ws + 0;               // 98,304
    float* wl      = ws + 98304;           // 2,048
    float* bias2p  = ws + 100352;          // 2,048
    float* biascat = ws + 102400;          // 64
    float* c       = ws + 102464;          // 262,144
    f16*   hAhi    = (f16*)(ws + 364608);  // 262,144 f16
    f16*   hAlo    = (f16*)(ws + 495680);
    f16*   hBhi    = (f16*)(ws + 626752);
    f16*   hBlo    = (f16*)(ws + 757824);
    f16*   Yhi     = (f16*)(ws + 889920);  // 512*144 f16
    f16*   Ylo     = (f16*)(ws + 926784);
    float* Y       = ws + 963648;          // 73,728 -> ends 1,037,376
    f16*   watthi  = (f16*)(ws + 1037376); // 512*1024 f16 = 262,144 fl
    f16*   wattlo  = (f16*)(ws + 1299520); // ends 1,561,664
    f16*   x0hi    = (f16*)(ws + 1563712); // 512*1056 f16
    f16*   x0lo    = (f16*)(ws + 1834048);
    f16*   embhi   = (f16*)(ws + 2104384); // 48*1056 f16
    f16*   emblo   = (f16*)(ws + 2129728); // ends 2,155,072
    const size_t SB = 2155072;

    // S hi/lo: persistent through setup (x0 gather + V GEMM). [SB .. SB+1,572,864)
    f16*   Shi     = (f16*)(ws + SB);               // 1536*1024 f16 = 786,432 fl
    f16*   Slo     = (f16*)(ws + SB + 786432);
    const size_t SB2 = SB + 1572864;                // 3,727,936

    // stage-1 (x0, two K-panels; ws floor >= 10,066,496 floats):
    //  panel R:   lwtR hi/lo  [1088][3072] at SB2 (3,342,336 fl) + Rhi/Rlo + x0part
    //  panel SY:  lwtSY hi/lo [1088][3232] at SB2 (3,516,416 fl, overwrites lwtR)
    f16*   lwtRh   = (f16*)(ws + SB2);              // 1,671,168 fl
    f16*   lwtRl   = (f16*)(ws + SB2 + 1671168);
    f16*   lwtSYh  = (f16*)(ws + SB2);              // 1,758,208 fl
    f16*   lwtSYl  = (f16*)(ws + SB2 + 1758208);    // panel ends <= 7,244,352
    f16*   Rhi     = (f16*)(ws + 7244352);          // 786,432 fl
    f16*   Rlo     = (f16*)(ws + 8030784);          // ends 8,817,216
    float* x0part  = ws + 8817216;                  // 2*512*1028 = 1,052,672 -> ends 9,869,888
    // stage-2 (scan; lwt/R/x0part dead by then):
    f16*   Wcthi   = (f16*)(ws + SB2);              // 540,672 fl
    f16*   Wctlo   = (f16*)(ws + SB2 + 540672);     // ends 4,809,280
    f16*   Wihphi  = (f16*)(ws + 4809280);          // 1,081,344 fl
    f16*   Wihplo  = (f16*)(ws + 5890624);          // ends 6,971,968
    float* Vbuf    = ws + 6971968;                  // 786,432 -> ends 7,758,400
    float* rawg    = ws + 7758400;                  // 2*512*2112 = 2,162,688 -> ends 9,921,088
    float* gpart   = ws + 7758400;                  // setup partials overlay rawg (gx0: 2,097,152)

    const int ZGX = 2, ksl_gx = 544;
    const int ZE  = 4, ksl_e  = 256;
    const int ZSC = 2, ksl_sc = 256;    // scan split-K: 2 (r7-measured best)

    // ---- setup ----
    k_prep<<<8,256,0,stream>>>(bih,bhh,bp,Wih,bias2p,biascat,wl);
    k_cls<<<K*B,64,0,stream>>>(S,R,clsW,clsb,Y);
    k_curr_action<<<(B*C+255)/256,256,0,stream>>>(Y,outca);
    k_cvtY<<<(B*144+255)/256,256,0,stream>>>(Y,Yhi,Ylo);
    k_dur0<<<B,256,0,stream>>>(R,durW,durb,outpad);
    // pre-convert S and R to f16 hi/lo ONCE (kills the 33x redundant in-GEMM conversion)
    k_cvt<<<(1536*1024+255)/256,256,0,stream>>>(S,Shi,Slo,1536,1024,1024,1024,1.f);
    k_cvt<<<(1536*1024+255)/256,256,0,stream>>>(R,Rhi,Rlo,1536,1024,1024,1024,1.f);
    // ---- x0 = feat @ linW, two K-panels ----
    // panel A: R-part (feat cols 3216..6288 -> K=3072), B = linW rows 3216.. transposed
    k_bt_build<<<dim3(96,34),256,0,stream>>>(linW+(size_t)3216*DP1,lwtRh,lwtRl,
                                             3072,DP1,DP1,1088,3072,1.f);
    k_gemm<32,1><<<8*33*2,256,0,stream>>>(nullptr,nullptr,lwtRh,lwtRl,x0part,nullptr,
                                          512,1028,3072,0,3072,1028,1536,(size_t)512*1028,8,2,0,
                                          nullptr,nullptr,Rhi,Rlo,0,3072);
    // panel B: Y+S part (feat cols 0..3216 -> K=3232 padded), accumulate into x0part
    k_bt_build<<<dim3(101,34),256,0,stream>>>(linW,lwtSYh,lwtSYl,3216,DP1,DP1,1088,3232,1.f);
    k_gemm<32,1><<<8*33*2,256,0,stream>>>(nullptr,nullptr,lwtSYh,lwtSYl,x0part,nullptr,
                                          512,1028,3232,0,3232,1028,1600,(size_t)512*1028,8,2,1,
                                          Yhi,Ylo,Shi,Slo,144,3216);
    // fused 2-part reduce + bias + hi/lo convert
    k_redcvt<<<(512*KP+255)/256,256,0,stream>>>(x0part,2,(size_t)512*1028,linb,x0hi,x0lo);
    // Wih^T (gate-perm rows) hi/lo   [lwt region dead from here]
    k_permrows<<<(G4H*KP+255)/256,256,0,stream>>>(Wih,Wihphi,Wihplo,DP1,KP,DP1);
    // gx0 = x0 @ WihT (split-K ZGX, partials in gpart)
    k_gemm<64,0><<<8*32*ZGX,256,0,stream>>>(x0hi,x0lo,Wihphi,Wihplo,gpart,nullptr,
                                            512,G4H,KP,KP,KP,G4H,ksl_gx,(size_t)512*G4H,8,ZGX,0,
                                            nullptr,nullptr,nullptr,nullptr,0,0);
    k_lstm0<<<(B*H+255)/256,256,0,stream>>>(gpart,ZGX,(size_t)512*G4H,bias2p,c,hAhi,hAlo);
    k_cvt<<<(48*KP+255)/256,256,0,stream>>>(embed,embhi,emblo,48,1024,1024,KP,1.f);
    // E = embed @ WihT + bias2p (partials reuse gpart after k_lstm0)
    k_gemm<64,0><<<1*32*ZE,256,0,stream>>>(embhi,emblo,Wihphi,Wihplo,gpart,nullptr,
                                           48,G4H,KP,KP,KP,G4H,ksl_e,(size_t)48*G4H,1,ZE,0,
                                           nullptr,nullptr,nullptr,nullptr,0,0);
    k_red<<<(48*G4H+255)/256,256,0,stream>>>(E,gpart,ZE,(size_t)48*G4H,48,G4H,G4H,bias2p);
    // V[k,b,:] = (S_k @ Wattn^T)/32  (reuses Shi/Slo)
    k_cvt<<<(512*1024+255)/256,256,0,stream>>>(Wattn,watthi,wattlo,512,1024,1024,1024,0.03125f);
    k_gemm<64,0><<<24*8,256,0,stream>>>(Shi,Slo,watthi,wattlo,Vbuf,nullptr,
                                        1536,512,1024,1024,1024,512,1024,0,24,1,0,
                                        nullptr,nullptr,nullptr,nullptr,0,0);
    // Wct2 [2112][512]: rows 0..2047 Whh perm | 2048..2095 Wp^T | 2096..2111 pad 0
    k_permrows<<<(G4H*512+255)/256,256,0,stream>>>(Whh,Wcthi,Wctlo,H,H,H);
    k_bt_build<<<dim3(16,2),256,0,stream>>>(Wp,Wcthi+(size_t)2048*512,Wctlo+(size_t)2048*512,
                                            512,48,48,48,512,1.f);
    k_zeroh<<<32,256,0,stream>>>(Wcthi+(size_t)2096*512,Wctlo+(size_t)2096*512,16*512);

    // ---- scan (r7 config: GEMM NT=32 ZSC=2 -> 1056 blocks ~4/CU; 512-thread postapply) ----
    size_t pstr = (size_t)512*NC;
    f16 *hCurHi=hAhi, *hCurLo=hAlo, *hPrvHi=hBhi, *hPrvLo=hBlo;
    for (int t=0;t<T;t++){
        k_gemm<32,0><<<8*66*ZSC,256,0,stream>>>(hCurHi,hCurLo,Wcthi,Wctlo,rawg,nullptr,
                                                512,NCV,H,H,H,NC,ksl_sc,pstr,8,ZSC,0,
                                                nullptr,nullptr,nullptr,nullptr,0,0);
        k_postapply<2><<<B,512,0,stream>>>(rawg,pstr,S,Vbuf,hCurHi,hCurLo,
                                        (t==0)?nullptr:hPrvHi,(t==0)?nullptr:hPrvLo,
                                        E,wl,biascat,Wdur,bdur,
                                        outlab,outprobs,outatt,outpad,
                                        c,hPrvHi,hPrvLo,t,(t<T-1)?1:0);
        f16* th=hPrvHi; hPrvHi=hCurHi; hCurHi=th;
        f16* tl=hPrvLo; hPrvLo=hCurLo; hCurLo=tl;
    }
}

// Round 11
// 847.927 us; speedup vs baseline: 1.0819x; 1.0428x over previous
//
#include <hip/hip_runtime.h>
#include <math.h>

#define B 512
#define D 1024
#define H 512
#define C 48
#define K 3
#define T 25
#define DP1 1025
#define G4H 2048
#define NC 2112         // step GEMM N (padded): 2048 gates | 48 logits | 16 pad
#define NCV 2096        // valid cols
#define KP 1056         // padded K for x0/embed rows (multiple of 32)
#define FK 6304         // padded feat-K (6288 -> 6304)

typedef _Float16 f16;
typedef _Float16 half8 __attribute__((ext_vector_type(8)));
typedef float floatx4 __attribute__((ext_vector_type(4)));

__device__ __forceinline__ float sigf(float x){ return 1.0f/(1.0f+__expf(-x)); }
// NaN-safe fast tanh
__device__ __forceinline__ float tanhf_fast(float x){
    float t = __expf(-2.0f*fabsf(x));
    float r = (1.0f-t)/(1.0f+t);
    return x<0.f ? -r : r;
}

// ================= unified split-f16 MFMA GEMM =================
// template<NT, MODE>: NT = n-tile (32/64); MODE 0 = plain A; MODE 1 = x0 feat gather
// (Y f16 + S/R f32 with conversion deferred to after the MFMA block).
// Counted-vmcnt pipeline: raw s_barrier + lgkmcnt-only wait (prefetch stays in flight).
// msel>0: B panel selected per mblk group (block-diagonal batched GEMM, used by cls).
template<int NT, int MODE>
__global__ __launch_bounds__(256)
void k_gemm(const f16* __restrict__ Ahi, const f16* __restrict__ Alo,
            const f16* __restrict__ Bhi_, const f16* __restrict__ Blo_,
            float* __restrict__ Cc, const float* __restrict__ bias,
            int M, int Nvalid, int Ktot, int lda, int ldb, int ldc,
            int ksl, size_t cstride, int MB, int Z, int zmaj, int msel, size_t bsel,
            const f16* __restrict__ Yh, const f16* __restrict__ Yl,
            const float* __restrict__ Sf, const float* __restrict__ Rf)
{
    __shared__ __align__(16) f16 Ash[2][64][40];
    __shared__ __align__(16) f16 Asl[2][64][40];
    __shared__ __align__(16) f16 Bsh[2][NT][40];
    __shared__ __align__(16) f16 Bsl[2][NT][40];
    int t = threadIdx.x;
    int mblk, nblk, z;
    if (zmaj){
        z = blockIdx.x % Z;
        int rest = blockIdx.x / Z;
        mblk = rest % MB; nblk = rest / MB;
    } else {
        int chunk = gridDim.x >> 3;
        int g = (blockIdx.x & 7)*chunk + (blockIdx.x >> 3);
        int mz = g % (MB*Z);
        nblk = g / (MB*Z);
        mblk = mz / Z;
        z    = mz % Z;
    }
    const f16* Bhi = Bhi_;
    const f16* Blo = Blo_;
    if (msel){ size_t so = (size_t)(mblk/msel)*bsel; Bhi += so; Blo += so; }
    int m0 = mblk*64, n0 = nblk*NT;
    int kbase = z*ksl;
    int kcnt = (z==Z-1)? (Ktot-kbase) : ksl;
    int nIter = kcnt >> 5;
    int r = t>>2, seg = t&3;
    const bool ldB = (r < NT);
    half8 rah, ral, rbh, rbl;
    float4 fA0, fA1;

    auto LOAD = [&](int k0){
        int kk = k0 + seg*8;
        if (ldB){
            size_t off = (size_t)(n0+r)*ldb + kbase + kk;
            rbh = *(const half8*)(Bhi + off);
            rbl = *(const half8*)(Blo + off);
        }
        int m = m0 + r;
        if (MODE==0){
            if (m < M){
                size_t off = (size_t)m*lda + kbase + kk;
                rah = *(const half8*)(Ahi + off);
                ral = *(const half8*)(Alo + off);
            } else {
                #pragma unroll
                for (int i=0;i<8;i++){ rah[i]=(f16)0; ral[i]=(f16)0; }
            }
        } else {
            int kabs = kbase + kk;   // 8-aligned; source runs never straddle boundaries
            if (kabs < 144){
                rah = *(const half8*)(Yh + (size_t)m*144 + kabs);
                ral = *(const half8*)(Yl + (size_t)m*144 + kabs);
            } else if (kabs < 6288){
                int kp = kabs - 144;
                const float* src = (kp < 3*D)
                    ? (Sf + (size_t)(kp>>10)*(B*D) + (size_t)m*D + (kp&(D-1)))
                    : (Rf + (size_t)((kp-3*D)>>10)*(B*D) + (size_t)m*D + ((kp-3*D)&(D-1)));
                fA0 = *(const float4*)src;     // raw; converted later (CONV)
                fA1 = *(const float4*)(src+4);
            } else {
                #pragma unroll
                for (int i=0;i<8;i++){ rah[i]=(f16)0; ral[i]=(f16)0; }
            }
        }
    };
    auto CONV = [&](int k0){     // MODE 1: convert S/R floats after MFMA block
        int kk = k0 + seg*8;
        int kabs = kbase + kk;
        if (kabs >= 144 && kabs < 6288){
            float fv[8]={fA0.x,fA0.y,fA0.z,fA0.w,fA1.x,fA1.y,fA1.z,fA1.w};
            #pragma unroll
            for (int i=0;i<8;i++){
                f16 h=(f16)fv[i];
                rah[i]=h; ral[i]=(f16)(fv[i]-(float)h);
            }
        }
    };

    LOAD(0);
    if (MODE==1) CONV(0);
    int lane = t&63, wv = t>>6;
    int lrow = lane&15, quad = lane>>4;
    floatx4 acc[NT/16] = {};
    int cur = 0;
    for (int it=0; it<nIter; ++it){
        *(half8*)&Ash[cur][r][seg*8] = rah;
        *(half8*)&Asl[cur][r][seg*8] = ral;
        if (ldB){
            *(half8*)&Bsh[cur][r][seg*8] = rbh;
            *(half8*)&Bsl[cur][r][seg*8] = rbl;
        }
        if (it+1 < nIter) LOAD((it+1)<<5);
        asm volatile("s_waitcnt lgkmcnt(0)" ::: "memory");
        __builtin_amdgcn_s_barrier();
        half8 ah = *(const half8*)&Ash[cur][wv*16+lrow][quad*8];
        half8 al = *(const half8*)&Asl[cur][wv*16+lrow][quad*8];
        #pragma unroll
        for (int j=0;j<NT/16;j++){
            half8 bh = *(const half8*)&Bsh[cur][j*16+lrow][quad*8];
            half8 bl = *(const half8*)&Bsl[cur][j*16+lrow][quad*8];
            acc[j] = __builtin_amdgcn_mfma_f32_16x16x32_f16(ah, bh, acc[j], 0,0,0);
            acc[j] = __builtin_amdgcn_mfma_f32_16x16x32_f16(al, bh, acc[j], 0,0,0);
            acc[j] = __builtin_amdgcn_mfma_f32_16x16x32_f16(ah, bl, acc[j], 0,0,0);
        }
        if (MODE==1 && it+1 < nIter) CONV((it+1)<<5);
        cur ^= 1;
    }
    float* Cz = Cc + (size_t)z*cstride;
    #pragma unroll
    for (int j=0;j<NT/16;j++){
        int col = n0 + j*16 + lrow;
        if (col >= Nvalid) continue;
        float bv = bias ? bias[col] : 0.f;
        #pragma unroll
        for (int i=0;i<4;i++){
            int row = m0 + wv*16 + quad*4 + i;
            if (row < M) Cz[(size_t)row*ldc + col] = acc[j][i] + bv;
        }
    }
}

// ================= setup kernels =================

__global__ void k_bt_build(const float* __restrict__ src, f16* __restrict__ hi, f16* __restrict__ lo,
                           int Ksrc, int Nsrc, int ld_src, int NB, int KB, float scale){
    __shared__ float tile[32][33];
    int k0 = blockIdx.x*32, n0 = blockIdx.y*32;
    int lx = threadIdx.x & 31, ly = threadIdx.x >> 5;
    for (int rr=0; rr<32; rr+=8){
        int k2 = k0+ly+rr, n = n0+lx;
        tile[ly+rr][lx] = (k2<Ksrc && n<Nsrc)? src[(size_t)k2*ld_src+n]*scale : 0.f;
    }
    __syncthreads();
    for (int rr=0; rr<32; rr+=8){
        int n = n0+ly+rr, k2 = k0+lx;
        if (n<NB && k2<KB){
            float v = tile[lx][ly+rr];
            f16 h=(f16)v;
            hi[(size_t)n*KB+k2]=h;
            lo[(size_t)n*KB+k2]=(f16)(v-(float)h);
        }
    }
}

__global__ void k_permrows(const float* __restrict__ src, f16* __restrict__ hi, f16* __restrict__ lo,
                           int src_ld, int dst_ld, int kvalid){
    int idx = blockIdx.x*256+threadIdx.x;
    if (idx >= G4H*dst_ld) return;
    int p = idx/dst_ld, k2 = idx%dst_ld;
    int j = p>>2, g = p&3, gi = (g<<9)|j;
    float v = (k2<kvalid)? src[(size_t)gi*src_ld + k2] : 0.f;
    f16 h=(f16)v;
    hi[idx]=h; lo[idx]=(f16)(v-(float)h);
}

__global__ void k_cvt(const float* __restrict__ src, f16* __restrict__ hi, f16* __restrict__ lo,
                      int M, int ld_src, int nvalid, int ld_dst, float scale){
    int idx = blockIdx.x*256+threadIdx.x;
    if (idx >= M*ld_dst) return;
    int m = idx/ld_dst, n = idx%ld_dst;
    float v = (n<nvalid)? src[(size_t)m*ld_src+n]*scale : 0.f;
    f16 h=(f16)v; hi[idx]=h; lo[idx]=(f16)(v-(float)h);
}

// cat(S,R) rows -> f16 hi/lo [1536][2048]
__global__ void k_cvtSR(const float* __restrict__ S, const float* __restrict__ R,
                        f16* __restrict__ hi, f16* __restrict__ lo){
    int idx = blockIdx.x*256+threadIdx.x;
    if (idx >= 1536*2048) return;
    int m = idx>>11, kk = idx&2047;
    float v = (kk<1024)? S[((size_t)m<<10)+kk] : R[((size_t)m<<10)+kk-1024];
    f16 h=(f16)v; hi[idx]=h; lo[idx]=(f16)(v-(float)h);
}

// cls partial reduce + bias + softmax -> Y[row][C]
__global__ __launch_bounds__(64)
void k_clssm(const float* __restrict__ part, const float* __restrict__ clsb,
             float* __restrict__ Y){
    int row = blockIdx.x, lane = threadIdx.x;
    float v = -3.0e38f;
    if (lane < C){
        float s = 0.f;
        #pragma unroll
        for (int z=0;z<4;z++) s += part[(size_t)z*(1536*64) + (size_t)row*64 + lane];
        v = s + clsb[(row>>9)*C + lane];
    }
    float m = v;
    #pragma unroll
    for (int s2=32;s2>0;s2>>=1) m = fmaxf(m, __shfl_xor(m,s2));
    float e = (lane<C)? expf(v-m) : 0.f;
    float ss = e;
    #pragma unroll
    for (int s2=32;s2>0;s2>>=1) ss += __shfl_xor(ss,s2);
    if (lane<C) Y[(size_t)row*C + lane] = e/ss;
}

__global__ void k_cvtY(const float* __restrict__ Y, f16* __restrict__ hi, f16* __restrict__ lo){
    int idx = blockIdx.x*256+threadIdx.x;
    if (idx >= B*144) return;
    int b = idx/144, k2 = idx%144;
    float v = Y[((size_t)(k2/C)*B + b)*C + (k2%C)];
    f16 h=(f16)v; hi[idx]=h; lo[idx]=(f16)(v-(float)h);
}

__global__ void k_zeroh(f16* a, f16* b2, int n){
    int i = blockIdx.x*256+threadIdx.x; if (i<n){ a[i]=(f16)0; b2[i]=(f16)0; }
}

__global__ void k_prep(const float* __restrict__ bih, const float* __restrict__ bhh,
                       const float* __restrict__ bp, const float* __restrict__ Wih,
                       float* __restrict__ bias2p, float* __restrict__ biascat,
                       float* __restrict__ wl){
    int i = blockIdx.x*256 + threadIdx.x;
    if (i < G4H){
        int g=i&3, j=i>>2; int gi=(g<<9)|j;
        bias2p[i]=bih[gi]+bhh[gi];
        wl[i]=Wih[(size_t)gi*DP1 + 1024];
    }
    if (i < C) biascat[i]=bp[i];
}

__global__ void k_curr_action(const float* __restrict__ Y, float* __restrict__ outca){
    int i = blockIdx.x*256+threadIdx.x; if (i>=B*C) return;
    int b=i/C, c2=i%C;
    outca[i] = Y[((size_t)0*B+b)*C+c2] + Y[((size_t)1*B+b)*C+c2] + Y[((size_t)2*B+b)*C+c2];
}

__global__ void k_dur0(const float* __restrict__ R, const float* __restrict__ durW,
                       const float* __restrict__ durb, float* __restrict__ outpad){
    int b = blockIdx.x; int t = threadIdx.x;
    __shared__ float red[256];
    float p=0.f;
    for (int i=t; i<K*D; i+=256){ int k=i>>10, d=i&1023; p += R[((size_t)k*B+b)*D+d]*durW[i]; }
    red[t]=p; __syncthreads();
    for (int s=128;s>0;s>>=1){ if(t<s) red[t]+=red[t+s]; __syncthreads(); }
    if (t==0) outpad[(size_t)b*(T+1)] = red[0] + durb[0];
}

__global__ void k_red(float* __restrict__ dst, const float* __restrict__ src, int parts, size_t pstride,
                      int M, int Nld, int Nvalid, const float* __restrict__ bias){
    int idx = blockIdx.x*256+threadIdx.x;
    if (idx >= M*Nld) return;
    int n = idx % Nld;
    float v = 0.f;
    if (n < Nvalid){
        for (int p=0;p<parts;p++) v += src[(size_t)p*pstride + idx];
        if (bias) v += bias[n];
    }
    dst[idx]=v;
}

__global__ void k_redcvt(const float* __restrict__ src, int parts, size_t pstride,
                         const float* __restrict__ bias, f16* __restrict__ hi, f16* __restrict__ lo){
    int idx = blockIdx.x*256+threadIdx.x;
    if (idx >= 512*KP) return;
    int m = idx/KP, n = idx%KP;
    float v = 0.f;
    if (n < DP1){
        for (int p=0;p<parts;p++) v += src[(size_t)p*pstride + (size_t)m*1028 + n];
        v += bias[n];
    }
    f16 h=(f16)v; hi[idx]=h; lo[idx]=(f16)(v-(float)h);
}

// ================= scan kernels =================

__global__ void k_lstm0(const float* __restrict__ gxp, int parts, size_t pstride,
                        const float* __restrict__ bias2p,
                        float* __restrict__ c, f16* __restrict__ hhi, f16* __restrict__ hlo){
    int idx = blockIdx.x*256+threadIdx.x; if (idx>=B*H) return;
    int r=idx>>9, j=idx&511;
    float4 g = *(const float4*)&gxp[(size_t)r*G4H + (j<<2)];
    if (parts==2){
        float4 g2 = *(const float4*)&gxp[pstride + (size_t)r*G4H + (j<<2)];
        g.x+=g2.x; g.y+=g2.y; g.z+=g2.z; g.w+=g2.w;
    }
    float4 bb = *(const float4*)&bias2p[j<<2];
    g.x+=bb.x; g.y+=bb.y; g.z+=bb.z; g.w+=bb.w;
    float cn = sigf(g.x)*tanhf_fast(g.z);
    c[idx]=cn;
    float hv = sigf(g.w)*tanhf_fast(cn);
    f16 h=(f16)hv; hhi[idx]=h; hlo[idx]=(f16)(hv-(float)h);
}

// fused: softmax/argmax + probs + attention (via precomputed V) + dur head + LSTM cell.
// 512 threads; wave-shfl reductions; PARTS-way split-K partial sum inline. (r7 config)
template<int PARTS>
__global__ void k_postapply(const float* __restrict__ rawg, size_t pstride,
                       const float* __restrict__ S, const float* __restrict__ V,
                       const f16* __restrict__ hchi, const f16* __restrict__ hclo,
                       const f16* __restrict__ holdhi, const f16* __restrict__ holdlo,
                       const float* __restrict__ E, const float* __restrict__ wl,
                       const float* __restrict__ biascat,
                       const float* __restrict__ Wdur, const float* __restrict__ bdur,
                       float* __restrict__ outlab, float* __restrict__ outprobs,
                       float* __restrict__ outatt, float* __restrict__ outpad,
                       float* __restrict__ c, f16* __restrict__ hNhi, f16* __restrict__ hNlo,
                       int tstep, int doLstm)
{
    int b=blockIdx.x, t=threadIdx.x;
    int lane=t&63, wv=t>>6;
    __shared__ float aw[3];
    __shared__ float redw[4][8];
    __shared__ int sbest;
    __shared__ float sdv;
    const float* z0 = rawg + (size_t)b*NC;
    if (t<64){
        float lgv = -3.0e38f;
        if (t<C){
            float v = 0.f;
            #pragma unroll
            for (int p=0;p<PARTS;p++) v += z0[(size_t)p*pstride + G4H + t];
            lgv = v + biascat[t];
        }
        float m = lgv; int bi = t;
        #pragma unroll
        for (int s2=32;s2>0;s2>>=1){
            float om=__shfl_xor(m,s2); int ob=__shfl_xor(bi,s2);
            if (om>m || (om==m && ob<bi)){ m=om; bi=ob; }
        }
        float e=(t<C)? __expf(lgv-m):0.f;
        float ss=e;
        #pragma unroll
        for (int s2=32;s2>0;s2>>=1) ss+=__shfl_xor(ss,s2);
        if (t<C) outprobs[(size_t)b*(T*C)+tstep*C+t]=e/ss;
        if (t==0){
            sbest=bi;
            outlab[(size_t)tstep*B+b]=(float)bi;
        }
    }
    float hv_t = (float)hchi[(size_t)b*H + t] + (float)hclo[(size_t)b*H + t];
    float p0 = hv_t * V[((size_t)(0*B+b))*H + t];
    float p1 = hv_t * V[((size_t)(1*B+b))*H + t];
    float p2 = hv_t * V[((size_t)(2*B+b))*H + t];
    #pragma unroll
    for (int s2=32;s2>0;s2>>=1){
        p0 += __shfl_xor(p0,s2); p1 += __shfl_xor(p1,s2); p2 += __shfl_xor(p2,s2);
    }
    if (lane==0){ redw[0][wv]=p0; redw[1][wv]=p1; redw[2][wv]=p2; }
    __syncthreads();
    if (t==0){
        float a0=0.f,a1=0.f,a2=0.f;
        #pragma unroll
        for (int w=0;w<8;w++){ a0+=redw[0][w]; a1+=redw[1][w]; a2+=redw[2][w]; }
        float m=fmaxf(a0,fmaxf(a1,a2));
        float e0=__expf(a0-m), e1=__expf(a1-m), e2=__expf(a2-m);
        float si=1.f/(e0+e1+e2);
        aw[0]=e0*si; aw[1]=e1*si; aw[2]=e2*si;
    }
    __syncthreads();
    float a0=aw[0],a1=aw[1],a2=aw[2];
    const float* S0  = S + (size_t)b*D;
    const float* S1  = S0 + (size_t)B*D;
    const float* S2p = S1 + (size_t)B*D;
    float dp = 0.f;
    float* attp = outatt + (size_t)tstep*B*D + (size_t)b*D;
    {
        int d = t<<1;
        float2 s0 = *(const float2*)(S0+d);
        float2 s1 = *(const float2*)(S1+d);
        float2 s2 = *(const float2*)(S2p+d);
        float2 w2 = *(const float2*)(Wdur+d);
        float2 av;
        av.x = a0*s0.x+a1*s1.x+a2*s2.x;
        av.y = a0*s0.y+a1*s1.y+a2*s2.y;
        *(float2*)(attp+d) = av;
        dp += av.x*w2.x+av.y*w2.y;
    }
    if (holdhi){
        float hvo = (float)holdhi[(size_t)b*H+t] + (float)holdlo[(size_t)b*H+t];
        dp += hvo * Wdur[D+t];
    }
    #pragma unroll
    for (int s2=32;s2>0;s2>>=1) dp += __shfl_xor(dp,s2);
    if (lane==0) redw[3][wv]=dp;
    __syncthreads();
    if (t==0){
        float dv=0.f;
        #pragma unroll
        for (int w=0;w<8;w++) dv+=redw[3][w];
        dv += bdur[0];
        outpad[(size_t)b*(T+1)+tstep+1]=dv; sdv=dv;
    }
    __syncthreads();
    if (doLstm){
        int lb=sbest; float dv=sdv;
        int j=t;
        float4 g4 = *(const float4*)&z0[4*j];
        #pragma unroll
        for (int p=1;p<PARTS;p++){
            float4 h4 = *(const float4*)&z0[(size_t)p*pstride + 4*j];
            g4.x+=h4.x; g4.y+=h4.y; g4.z+=h4.z; g4.w+=h4.w;
        }
        float4 e4 = *(const float4*)&E[(size_t)lb*G4H+4*j];
        float4 w4 = *(const float4*)&wl[4*j];
        float gi = g4.x+e4.x+dv*w4.x;
        float gf = g4.y+e4.y+dv*w4.y;
        float gg = g4.z+e4.z+dv*w4.z;
        float go = g4.w+e4.w+dv*w4.w;
        size_t ci=(size_t)b*H+j;
        float cn = sigf(gf)*c[ci] + sigf(gi)*tanhf_fast(gg);
        c[ci]=cn;
        float hv = sigf(go)*tanhf_fast(cn);
        f16 hh=(f16)hv;
        hNhi[ci]=hh; hNlo[ci]=(f16)(hv-(float)hh);
    }
}

// ================= host =================

extern "C" void kernel_launch(void* const* d_in, const int* in_sizes, int n_in,
                              void* d_out, int out_size, void* d_ws, size_t ws_size,
                              hipStream_t stream) {
    const float* S    = (const float*)d_in[0];
    const float* R    = (const float*)d_in[1];
    const float* clsW = (const float*)d_in[2];
    const float* clsb = (const float*)d_in[3];
    const float* durW = (const float*)d_in[4];
    const float* durb = (const float*)d_in[5];
    const float* linW = (const float*)d_in[6];
    const float* linb = (const float*)d_in[7];
    const float* Wih  = (const float*)d_in[8];
    const float* Whh  = (const float*)d_in[9];
    const float* bih  = (const float*)d_in[10];
    const float* bhh  = (const float*)d_in[11];
    const float* Wp   = (const float*)d_in[12];
    const float* bp   = (const float*)d_in[13];
    const float* Wdur = (const float*)d_in[14];
    const float* bdur = (const float*)d_in[15];
    const float* embed= (const float*)d_in[16];
    const float* Wattn= (const float*)d_in[17];

    float* out = (float*)d_out;
    float* outlab   = out;                 // [T,B]
    float* outprobs = out + 12800;         // [B,T,C]
    float* outca    = out + 627200;        // [B,C]
    float* outpad   = out + 651776;        // [B,T+1]
    float* outatt   = out + 665088;        // [T,B,D]

    float* ws = (float*)d_ws;
    // persistent block [0 .. 2,155,072)
    float* E       = ws + 0;               // 98,304
    float* wl      = ws + 98304;           // 2,048
    float* bias2p  = ws + 100352;          // 2,048
    float* biascat = ws + 102400;          // 64
    float* c       = ws + 102464;          // 262,144
    f16*   hAhi    = (f16*)(ws + 364608);  // 262,144 f16
    f16*   hAlo    = (f16*)(ws + 495680);
    f16*   hBhi    = (f16*)(ws + 626752);
    f16*   hBlo    = (f16*)(ws + 757824);
    f16*   Yhi     = (f16*)(ws + 889920);  // 512*144 f16
    f16*   Ylo     = (f16*)(ws + 926784);
    float* Y       = ws + 963648;          // 73,728 -> ends 1,037,376
    f16*   watthi  = (f16*)(ws + 1037376); // 512*1024 f16
    f16*   wattlo  = (f16*)(ws + 1299520); // ends 1,561,664
    f16*   x0hi    = (f16*)(ws + 1563712); // 512*1056 f16
    f16*   x0lo    = (f16*)(ws + 1834048);
    f16*   embhi   = (f16*)(ws + 2104384); // 48*1056 f16
    f16*   emblo   = (f16*)(ws + 2129728); // ends 2,155,072
    const size_t SB = 2155072;

    // stage-0 (cls, dead before lwt build): SRcat hi/lo + clsWt hi/lo + clspart
    f16*   srch    = (f16*)(ws + SB);               // 1536*2048 f16 = 1,572,864 fl
    f16*   srcl    = (f16*)(ws + SB + 1572864);     // ends SB+3,145,728
    f16*   cwth    = (f16*)(ws + SB + 3145728);     // 3*64*2048 f16 = 196,608 fl
    f16*   cwtl    = (f16*)(ws + SB + 3342336);     // ends SB+3,538,944
    float* clspart = ws + SB + 3538944;             // 4*1536*64 = 393,216 -> ends SB+3,932,160

    // stage-1 (x0): lwt hi/lo [1088][6304] + x0part (ZX0-gated); ends exactly at 40.26MB floor
    f16*   lwthi   = (f16*)(ws + SB);               // 3,429,376 fl
    f16*   lwtlo   = (f16*)(ws + SB + 3429376);     // ends SB+6,858,752
    float* x0part  = ws + SB + 6858752;             // ZX0*512*1028

    // stage-2 (scan): Wct | S hi/lo | V | Wihp (setup) / rawg (scan) | gpart
    f16*   Wcthi   = (f16*)(ws + SB);               // 540,672 fl
    f16*   Wctlo   = (f16*)(ws + SB + 540672);      // ends SB+1,081,344
    f16*   Shi     = (f16*)(ws + SB + 1081344);     // 786,432 fl
    f16*   Slo     = (f16*)(ws + SB + 1867776);     // ends SB+2,654,208
    float* Vbuf    = ws + SB + 2654208;             // 786,432 -> ends SB+3,440,640
    f16*   Wihphi  = (f16*)(ws + SB + 3440640);     // 1,081,344 fl (setup only)
    f16*   Wihplo  = (f16*)(ws + SB + 4521984);     // ends SB+5,603,328
    float* rawg    = ws + SB + 3440640;             // scan: 2*512*2112 (overlays dead Wihp)
    float* gpart   = ws + SB + 5603328;             // setup partials

    // ---- workspace-gated split-K config for x0 ----
    int ZX0, ksl_x0;
    if      (ws_size >= (size_t)52898048){ ZX0=8; ksl_x0=800;  }
    else if (ws_size >= (size_t)44476672){ ZX0=4; ksl_x0=1600; }
    else                                 { ZX0=2; ksl_x0=3168; }
    const int ZGX = 2, ksl_gx = 544;
    const int ZE  = 4, ksl_e  = 256;
    const int ZSC = 2, ksl_sc = 256;

    // ---- stage 0: cls via MFMA (replaces 52us k_cls) ----
    k_prep<<<8,256,0,stream>>>(bih,bhh,bp,Wih,bias2p,biascat,wl);
    k_cvtSR<<<(1536*2048+255)/256,256,0,stream>>>(S,R,srch,srcl);
    for (int k=0;k<K;k++)
        k_bt_build<<<dim3(64,2),256,0,stream>>>(clsW+(size_t)k*2048*C,
                                                cwth+(size_t)k*64*2048, cwtl+(size_t)k*64*2048,
                                                2048,C,C,64,2048,1.f);
    // block-diagonal batched GEMM: M=1536 (3 groups of 8 mblks), B panel per group via msel
    k_gemm<32,0><<<24*4*2,256,0,stream>>>(srch,srcl,cwth,cwtl,clspart,nullptr,
                                          1536,C,2048,2048,2048,64,512,(size_t)1536*64,24,4,0,
                                          8,(size_t)64*2048,
                                          nullptr,nullptr,nullptr,nullptr);
    k_clssm<<<1536,64,0,stream>>>(clspart,clsb,Y);
    k_curr_action<<<(B*C+255)/256,256,0,stream>>>(Y,outca);
    k_cvtY<<<(B*144+255)/256,256,0,stream>>>(Y,Yhi,Ylo);
    k_dur0<<<B,256,0,stream>>>(R,durW,durb,outpad);

    // ---- stage 1: x0 = feat @ linW (single panel, r8 config) ----
    k_bt_build<<<dim3((FK+31)/32,(1088+31)/32),256,0,stream>>>(linW,lwthi,lwtlo,6288,1025,1025,1088,FK,1.f);
    k_gemm<32,1><<<8*33*ZX0,256,0,stream>>>(nullptr,nullptr,lwthi,lwtlo,x0part,nullptr,
                                            512,1028,FK,0,FK,1028,ksl_x0,(size_t)512*1028,8,ZX0,1,0,0,
                                            Yhi,Ylo,S,R);
    k_redcvt<<<(512*KP+255)/256,256,0,stream>>>(x0part,ZX0,(size_t)512*1028,linb,x0hi,x0lo);

    // ---- stage 2: scan prep ----
    k_permrows<<<(G4H*KP+255)/256,256,0,stream>>>(Wih,Wihphi,Wihplo,DP1,KP,DP1);
    k_gemm<64,0><<<8*32*ZGX,256,0,stream>>>(x0hi,x0lo,Wihphi,Wihplo,gpart,nullptr,
                                            512,G4H,KP,KP,KP,G4H,ksl_gx,(size_t)512*G4H,8,ZGX,0,0,0,
                                            nullptr,nullptr,nullptr,nullptr);
    k_lstm0<<<(B*H+255)/256,256,0,stream>>>(gpart,ZGX,(size_t)512*G4H,bias2p,c,hAhi,hAlo);
    k_cvt<<<(48*KP+255)/256,256,0,stream>>>(embed,embhi,emblo,48,1024,1024,KP,1.f);
    k_gemm<64,0><<<1*32*ZE,256,0,stream>>>(embhi,emblo,Wihphi,Wihplo,gpart,nullptr,
                                           48,G4H,KP,KP,KP,G4H,ksl_e,(size_t)48*G4H,1,ZE,0,0,0,
                                           nullptr,nullptr,nullptr,nullptr);
    k_red<<<(48*G4H+255)/256,256,0,stream>>>(E,gpart,ZE,(size_t)48*G4H,48,G4H,G4H,bias2p);
    // V[k,b,:] = (S_k @ Wattn^T)/32
    k_cvt<<<(1536*1024+255)/256,256,0,stream>>>(S,Shi,Slo,1536,1024,1024,1024,1.f);
    k_cvt<<<(512*1024+255)/256,256,0,stream>>>(Wattn,watthi,wattlo,512,1024,1024,1024,0.03125f);
    k_gemm<64,0><<<24*8,256,0,stream>>>(Shi,Slo,watthi,wattlo,Vbuf,nullptr,
                                        1536,512,1024,1024,1024,512,1024,0,24,1,0,0,0,
                                        nullptr,nullptr,nullptr,nullptr);
    // Wct2 [2112][512]
    k_permrows<<<(G4H*512+255)/256,256,0,stream>>>(Whh,Wcthi,Wctlo,H,H,H);
    k_bt_build<<<dim3(16,2),256,0,stream>>>(Wp,Wcthi+(size_t)2048*512,Wctlo+(size_t)2048*512,
                                            512,48,48,48,512,1.f);
    k_zeroh<<<32,256,0,stream>>>(Wcthi+(size_t)2096*512,Wctlo+(size_t)2096*512,16*512);

    // ---- scan (r7 config) ----
    size_t pstr = (size_t)512*NC;
    f16 *hCurHi=hAhi, *hCurLo=hAlo, *hPrvHi=hBhi, *hPrvLo=hBlo;
    for (int t=0;t<T;t++){
        k_gemm<32,0><<<8*66*ZSC,256,0,stream>>>(hCurHi,hCurLo,Wcthi,Wctlo,rawg,nullptr,
                                                512,NCV,H,H,H,NC,ksl_sc,pstr,8,ZSC,0,0,0,
                                                nullptr,nullptr,nullptr,nullptr);
        k_postapply<2><<<B,512,0,stream>>>(rawg,pstr,S,Vbuf,hCurHi,hCurLo,
                                        (t==0)?nullptr:hPrvHi,(t==0)?nullptr:hPrvLo,
                                        E,wl,biascat,Wdur,bdur,
                                        outlab,outprobs,outatt,outpad,
                                        c,hPrvHi,hPrvLo,t,(t<T-1)?1:0);
        f16* th=hPrvHi; hPrvHi=hCurHi; hCurHi=th;
        f16* tl=hPrvLo; hPrvLo=hCurLo; hCurLo=tl;
    }
}